// Round 1
// baseline (465.359 us; speedup 1.0000x reference)
//
#include <hip/hip_runtime.h>
#include <math.h>

#define BN 12
#define HG 28
#define WG 60
#define LL 1680      // HG*WG
#define CC 128
#define P2 20
#define HID 256

static constexpr size_t OUT_CAM_OFF = (size_t)BN * LL * P2 * CC;            // 51609600
static constexpr size_t OUT_PTS_OFF = OUT_CAM_OFF + (size_t)BN * LL * P2 * 2; // 52416000

// ---------------- transpose img_features (BN,C,L) -> (BN,L,C) ----------------
__global__ __launch_bounds__(256) void transpose_feat_k(const float* __restrict__ in,
                                                        float* __restrict__ out) {
  __shared__ float tile[64][65];
  const int bn = blockIdx.z;
  const int c0 = blockIdx.y * 64;
  const int l0 = blockIdx.x * 64;
  const int t = threadIdx.x;
  {
    const int lx = t & 63;
    const int cy = t >> 6;
#pragma unroll
    for (int i = 0; i < 64; i += 4) {
      const int c = c0 + cy + i;
      const int l = l0 + lx;
      float v = 0.f;
      if (l < LL) v = in[((size_t)bn * CC + c) * LL + l];
      tile[cy + i][lx] = v;
    }
  }
  __syncthreads();
  {
    const int cx = t & 63;
    const int ly = t >> 6;
#pragma unroll
    for (int i = 0; i < 64; i += 4) {
      const int l = l0 + ly + i;
      const int c = c0 + cx;
      if (l < LL) out[((size_t)bn * LL + l) * CC + c] = tile[cx][ly + i];
    }
  }
}

// ---------------- main fused kernel: one block per (bn, l) query ----------------
template <bool TR>
__global__ __launch_bounds__(128) void gauss_main(
    const float* __restrict__ means3D,
    const float* __restrict__ feat,   // TR ? (BN,L,C) : (BN,C,H,W)
    const float* __restrict__ dvec,
    const float* __restrict__ cov3D,
    const float* __restrict__ l2i,
    const float* __restrict__ W1,
    const float* __restrict__ b1,
    const float* __restrict__ W2,
    const float* __restrict__ b2,
    float* __restrict__ out) {
  const int l = blockIdx.x;
  const int bn = blockIdx.y;
  const int tid = threadIdx.x;

  __shared__ float sH[P2][HID];   // hidden activations
  __shared__ float sPn[P2][3];
  __shared__ float sW[P2][4];     // validity-masked bilinear weights
  __shared__ int sOff[P2][4];     // clamped (y*WG+x) offsets

  // ---- phase 1: geometry, projection, outputs 2+3, sample prep (threads 0..19)
  if (tid < P2) {
    const int p = tid;
    const size_t base3 = ((size_t)bn * LL + l) * 3;
    const float m0 = means3D[base3 + 0], m1 = means3D[base3 + 1], m2 = means3D[base3 + 2];
    const float d0 = dvec[base3 + 0], d1 = dvec[base3 + 1], d2 = dvec[base3 + 2];
    const float* cv = cov3D + ((size_t)bn * LL + l) * 9;
    const float q = d0 * (cv[0] * d0 + cv[1] * d1 + cv[2] * d2) +
                    d1 * (cv[3] * d0 + cv[4] * d1 + cv[5] * d2) +
                    d2 * (cv[6] * d0 + cv[7] * d1 + cv[8] * d2);
    const float s = sqrtf(q);
    const int k = p >> 2, j = p & 3;
    const float a = (-1.5f + 0.75f * (float)k) * s;       // lin5[k] * sqrt(q)
    const float tt = -0.5f + (1.0f / 3.0f) * (float)j;    // linP[j]
    // orth = (dv1, -dv0, 0)
    const float px = m0 + a * d0 + tt * d1;
    const float py = m1 + a * d1 - tt * d0;
    const float pz = m2 + a * d2;
    const float* M = l2i + (size_t)bn * 16;
    const float cx = M[0] * px + M[1] * py + M[2] * pz + M[3];
    const float cy = M[4] * px + M[5] * py + M[6] * pz + M[7];
    const float cz = M[8] * px + M[9] * py + M[10] * pz + M[11];
    const float homo = fmaxf(cz, 1e-6f);
    const float u = cx / homo;
    const float v = cy / homo;

    float* camo = out + OUT_CAM_OFF + (((size_t)bn * LL + l) * P2 + p) * 2;
    camo[0] = u;
    camo[1] = v;
    float* ptso = out + OUT_PTS_OFF + (((size_t)bn * LL + l) * P2 + p) * 3;
    ptso[0] = px;
    ptso[1] = py;
    ptso[2] = pz;

    // pixel coords in feature grid: x = u/8 - 0.5, y = v/8 - 0.5
    const float x = u * 0.125f - 0.5f;
    const float y = v * 0.125f - 0.5f;
    const float x0f = floorf(x), y0f = floorf(y);
    const float wx = x - x0f, wy = y - y0f;
    const bool vx0 = (x0f >= 0.f) && (x0f < (float)WG);
    const bool vx1 = (x0f + 1.f >= 0.f) && (x0f + 1.f < (float)WG);
    const bool vy0 = (y0f >= 0.f) && (y0f < (float)HG);
    const bool vy1 = (y0f + 1.f >= 0.f) && (y0f + 1.f < (float)HG);
    const float xc0 = fminf(fmaxf(x0f, 0.f), (float)(WG - 1));
    const float xc1 = fminf(fmaxf(x0f + 1.f, 0.f), (float)(WG - 1));
    const float yc0 = fminf(fmaxf(y0f, 0.f), (float)(HG - 1));
    const float yc1 = fminf(fmaxf(y0f + 1.f, 0.f), (float)(HG - 1));
    const int ix0 = (int)xc0, ix1 = (int)xc1, iy0 = (int)yc0, iy1 = (int)yc1;
    sOff[p][0] = iy0 * WG + ix0;
    sOff[p][1] = iy0 * WG + ix1;
    sOff[p][2] = iy1 * WG + ix0;
    sOff[p][3] = iy1 * WG + ix1;
    sW[p][0] = (vx0 && vy0) ? (1.f - wx) * (1.f - wy) : 0.f;
    sW[p][1] = (vx1 && vy0) ? wx * (1.f - wy) : 0.f;
    sW[p][2] = (vx0 && vy1) ? (1.f - wx) * wy : 0.f;
    sW[p][3] = (vx1 && vy1) ? wx * wy : 0.f;
    sPn[p][0] = fminf(fmaxf((px + 50.f) * 0.01f, 0.f), 1.f);
    sPn[p][1] = fminf(fmaxf((py + 50.f) * 0.01f, 0.f), 1.f);
    sPn[p][2] = fminf(fmaxf((pz + 4.f) * 0.125f, 0.f), 1.f);
  }
  __syncthreads();

  // ---- phase 2: hidden layer H[20][256] = relu(pn @ W1 + b1)
  for (int u0 = tid; u0 < P2 * HID; u0 += 128) {
    const int p = u0 >> 8;
    const int h = u0 & (HID - 1);
    const float v = b1[h] + sPn[p][0] * W1[h] + sPn[p][1] * W1[HID + h] + sPn[p][2] * W1[2 * HID + h];
    sH[p][h] = fmaxf(v, 0.f);
  }
  __syncthreads();

  // ---- phase 3: layer 2 (register-tiled 5 pts x 4 ch per thread) + bilinear + write
  const int pg = tid >> 5;          // 0..3   -> points pg*5 .. pg*5+4
  const int c0 = (tid & 31) * 4;    // channel group
  const int pbase = pg * 5;

  float acc[5][4];
#pragma unroll
  for (int i = 0; i < 5; ++i)
#pragma unroll
    for (int j2 = 0; j2 < 4; ++j2) acc[i][j2] = 0.f;

  for (int h = 0; h < HID; h += 4) {
    const float4 w0 = *(const float4*)(W2 + (size_t)(h + 0) * CC + c0);
    const float4 w1 = *(const float4*)(W2 + (size_t)(h + 1) * CC + c0);
    const float4 w2 = *(const float4*)(W2 + (size_t)(h + 2) * CC + c0);
    const float4 w3 = *(const float4*)(W2 + (size_t)(h + 3) * CC + c0);
#pragma unroll
    for (int i = 0; i < 5; ++i) {
      const float4 hv = *(const float4*)(&sH[pbase + i][h]);
      acc[i][0] += hv.x * w0.x + hv.y * w1.x + hv.z * w2.x + hv.w * w3.x;
      acc[i][1] += hv.x * w0.y + hv.y * w1.y + hv.z * w2.y + hv.w * w3.y;
      acc[i][2] += hv.x * w0.z + hv.y * w1.z + hv.z * w2.z + hv.w * w3.z;
      acc[i][3] += hv.x * w0.w + hv.y * w1.w + hv.z * w2.w + hv.w * w3.w;
    }
  }

  const float4 bias = *(const float4*)(b2 + c0);
  const float* fbase = feat + (size_t)bn * CC * LL;  // same total stride both layouts
#pragma unroll
  for (int i = 0; i < 5; ++i) {
    const int p = pbase + i;
    float4 r;
    r.x = acc[i][0] + bias.x;
    r.y = acc[i][1] + bias.y;
    r.z = acc[i][2] + bias.z;
    r.w = acc[i][3] + bias.w;
#pragma unroll
    for (int corner = 0; corner < 4; ++corner) {
      const float w = sW[p][corner];
      const int off = sOff[p][corner];
      if (TR) {
        const float4 f = *(const float4*)(fbase + (size_t)off * CC + c0);
        r.x += w * f.x;
        r.y += w * f.y;
        r.z += w * f.z;
        r.w += w * f.w;
      } else {
        r.x += w * fbase[(size_t)(c0 + 0) * LL + off];
        r.y += w * fbase[(size_t)(c0 + 1) * LL + off];
        r.z += w * fbase[(size_t)(c0 + 2) * LL + off];
        r.w += w * fbase[(size_t)(c0 + 3) * LL + off];
      }
    }
    *(float4*)(out + (((size_t)bn * LL + l) * P2 + p) * CC + c0) = r;
  }
}

extern "C" void kernel_launch(void* const* d_in, const int* in_sizes, int n_in,
                              void* d_out, int out_size, void* d_ws, size_t ws_size,
                              hipStream_t stream) {
  const float* means3D = (const float*)d_in[0];
  const float* img = (const float*)d_in[1];
  const float* dvec = (const float*)d_in[2];
  const float* cov3D = (const float*)d_in[3];
  const float* l2i = (const float*)d_in[4];
  const float* W1 = (const float*)d_in[5];
  const float* b1 = (const float*)d_in[6];
  const float* W2 = (const float*)d_in[7];
  const float* b2 = (const float*)d_in[8];
  float* out = (float*)d_out;

  const size_t tbytes = (size_t)BN * LL * CC * sizeof(float);
  if (ws_size >= tbytes) {
    float* featT = (float*)d_ws;
    hipLaunchKernelGGL(transpose_feat_k, dim3((LL + 63) / 64, CC / 64, BN), dim3(256), 0,
                       stream, img, featT);
    hipLaunchKernelGGL((gauss_main<true>), dim3(LL, BN), dim3(128), 0, stream, means3D, featT,
                       dvec, cov3D, l2i, W1, b1, W2, b2, out);
  } else {
    hipLaunchKernelGGL((gauss_main<false>), dim3(LL, BN), dim3(128), 0, stream, means3D, img,
                       dvec, cov3D, l2i, W1, b1, W2, b2, out);
  }
}

// Round 2
// 146.316 us; speedup vs baseline: 3.1805x; 3.1805x over previous
//
#include <hip/hip_runtime.h>
#include <math.h>

#define BN 12
#define HG 28
#define WG 60
#define LL 1680      // HG*WG
#define CC 128
#define P2 20
#define HID 256
#define NQB 4        // queries per block
#define NP (NQB * P2) // 80 points per block

static constexpr size_t OUT_CAM_OFF = (size_t)BN * LL * P2 * CC;              // 51609600
static constexpr size_t OUT_PTS_OFF = OUT_CAM_OFF + (size_t)BN * LL * P2 * 2; // 52416000

typedef short v8s __attribute__((ext_vector_type(8)));
typedef float v4f __attribute__((ext_vector_type(4)));

__device__ __forceinline__ unsigned short f2bf(float f) {
  unsigned x = __float_as_uint(f);
  unsigned r = (x + 0x7FFFu + ((x >> 16) & 1u)) >> 16;
  return (unsigned short)r;
}

// ---------------- transpose img_features (BN,C,L) -> (BN,L,C) ----------------
__global__ __launch_bounds__(256) void transpose_feat_k(const float* __restrict__ in,
                                                        float* __restrict__ out) {
  __shared__ float tile[64][65];
  const int bn = blockIdx.z;
  const int c0 = blockIdx.y * 64;
  const int l0 = blockIdx.x * 64;
  const int t = threadIdx.x;
  {
    const int lx = t & 63;
    const int cy = t >> 6;
#pragma unroll
    for (int i = 0; i < 64; i += 4) {
      const int c = c0 + cy + i;
      const int l = l0 + lx;
      float v = 0.f;
      if (l < LL) v = in[((size_t)bn * CC + c) * LL + l];
      tile[cy + i][lx] = v;
    }
  }
  __syncthreads();
  {
    const int cx = t & 63;
    const int ly = t >> 6;
#pragma unroll
    for (int i = 0; i < 64; i += 4) {
      const int l = l0 + ly + i;
      const int c = c0 + cx;
      if (l < LL) out[((size_t)bn * LL + l) * CC + c] = tile[cx][ly + i];
    }
  }
}

// ---------------- pack W2 (256x128 f32) into bf16 B-fragment order ----------------
// Entry t in [0,4096): cg = t>>9 (col group of 16), ks = (t>>6)&7, lane = t&63.
// lane's 8 bf16: W2[ks*32 + (lane>>4)*8 + e][cg*16 + (lane&15)], e=0..7.
__global__ __launch_bounds__(256) void pack_w2_k(const float* __restrict__ W2,
                                                 unsigned short* __restrict__ W2bf) {
  const int t = blockIdx.x * 256 + threadIdx.x;
  if (t >= 4096) return;
  const int lane = t & 63;
  const int ks = (t >> 6) & 7;
  const int cg = t >> 9;
  const int col = cg * 16 + (lane & 15);
  const int kb = ks * 32 + (lane >> 4) * 8;
  v8s r;
#pragma unroll
  for (int e = 0; e < 8; ++e) r[e] = (short)f2bf(W2[(size_t)(kb + e) * CC + col]);
  *(v8s*)(W2bf + (size_t)t * 8) = r;
}

// ---------------- main fused kernel: 4 queries (80 points) per block, MFMA MLP ----------
__global__ __launch_bounds__(256, 3) void gauss_mfma(
    const float* __restrict__ means3D,
    const float* __restrict__ featT,   // (BN,L,C)
    const float* __restrict__ dvec,
    const float* __restrict__ cov3D,
    const float* __restrict__ l2i,
    const float* __restrict__ W1,
    const float* __restrict__ b1,
    const unsigned short* __restrict__ W2bf,
    const float* __restrict__ b2,
    float* __restrict__ out) {
  const int tid = threadIdx.x;
  const int bn = blockIdx.x / (LL / NQB);  // 1680/4=420 blocks per bn; blocks never span bn

  __shared__ __align__(16) char sHraw[NP * 512];  // bf16 H[80][256], XOR-swizzled rows
  __shared__ float sW[NP][4];
  __shared__ int sOff[NP][4];
  __shared__ float sPn[NP][3];

  // ---- phase 1: geometry, projection, cam/pts outputs, sample prep (threads 0..79)
  if (tid < NP) {
    const int lp = tid;
    const int ql = lp / P2;
    const int p = lp - ql * P2;
    const int qg = blockIdx.x * NQB + ql;
    const size_t base3 = (size_t)qg * 3;
    const float m0 = means3D[base3 + 0], m1 = means3D[base3 + 1], m2 = means3D[base3 + 2];
    const float d0 = dvec[base3 + 0], d1 = dvec[base3 + 1], d2 = dvec[base3 + 2];
    const float* cv = cov3D + (size_t)qg * 9;
    const float q = d0 * (cv[0] * d0 + cv[1] * d1 + cv[2] * d2) +
                    d1 * (cv[3] * d0 + cv[4] * d1 + cv[5] * d2) +
                    d2 * (cv[6] * d0 + cv[7] * d1 + cv[8] * d2);
    const float s = sqrtf(q);
    const int k = p >> 2, j = p & 3;
    const float a = (-1.5f + 0.75f * (float)k) * s;     // lin5[k]*sqrt(q)
    const float tt = -0.5f + (1.0f / 3.0f) * (float)j;  // linP[j]
    const float px = m0 + a * d0 + tt * d1;
    const float py = m1 + a * d1 - tt * d0;
    const float pz = m2 + a * d2;
    const float* M = l2i + (size_t)bn * 16;
    const float cx = M[0] * px + M[1] * py + M[2] * pz + M[3];
    const float cy = M[4] * px + M[5] * py + M[6] * pz + M[7];
    const float cz = M[8] * px + M[9] * py + M[10] * pz + M[11];
    const float homo = fmaxf(cz, 1e-6f);
    const float u = cx / homo;
    const float v = cy / homo;

    const size_t ptg = (size_t)qg * P2 + p;
    float* camo = out + OUT_CAM_OFF + ptg * 2;
    camo[0] = u;
    camo[1] = v;
    float* ptso = out + OUT_PTS_OFF + ptg * 3;
    ptso[0] = px;
    ptso[1] = py;
    ptso[2] = pz;

    const float x = u * 0.125f - 0.5f;
    const float y = v * 0.125f - 0.5f;
    const float x0f = floorf(x), y0f = floorf(y);
    const float wx = x - x0f, wy = y - y0f;
    const bool vx0 = (x0f >= 0.f) && (x0f < (float)WG);
    const bool vx1 = (x0f + 1.f >= 0.f) && (x0f + 1.f < (float)WG);
    const bool vy0 = (y0f >= 0.f) && (y0f < (float)HG);
    const bool vy1 = (y0f + 1.f >= 0.f) && (y0f + 1.f < (float)HG);
    const int ix0 = (int)fminf(fmaxf(x0f, 0.f), (float)(WG - 1));
    const int ix1 = (int)fminf(fmaxf(x0f + 1.f, 0.f), (float)(WG - 1));
    const int iy0 = (int)fminf(fmaxf(y0f, 0.f), (float)(HG - 1));
    const int iy1 = (int)fminf(fmaxf(y0f + 1.f, 0.f), (float)(HG - 1));
    sOff[lp][0] = iy0 * WG + ix0;
    sOff[lp][1] = iy0 * WG + ix1;
    sOff[lp][2] = iy1 * WG + ix0;
    sOff[lp][3] = iy1 * WG + ix1;
    sW[lp][0] = (vx0 && vy0) ? (1.f - wx) * (1.f - wy) : 0.f;
    sW[lp][1] = (vx1 && vy0) ? wx * (1.f - wy) : 0.f;
    sW[lp][2] = (vx0 && vy1) ? (1.f - wx) * wy : 0.f;
    sW[lp][3] = (vx1 && vy1) ? wx * wy : 0.f;
    sPn[lp][0] = fminf(fmaxf((px + 50.f) * 0.01f, 0.f), 1.f);
    sPn[lp][1] = fminf(fmaxf((py + 50.f) * 0.01f, 0.f), 1.f);
    sPn[lp][2] = fminf(fmaxf((pz + 4.f) * 0.125f, 0.f), 1.f);
  }
  __syncthreads();

  // ---- phase 2: H[80][256] = relu(pn @ W1 + b1) -> bf16 LDS (swizzled)
#pragma unroll
  for (int it = 0; it < (NP * 128) / 256; ++it) {
    const int u0 = it * 256 + tid;
    const int h2 = u0 & 127;  // pair of hidden units
    const int p = u0 >> 7;
    const float2 bb = *(const float2*)(b1 + 2 * h2);
    const float2 w0 = *(const float2*)(W1 + 2 * h2);
    const float2 w1v = *(const float2*)(W1 + HID + 2 * h2);
    const float2 w2v = *(const float2*)(W1 + 2 * HID + 2 * h2);
    const float pn0 = sPn[p][0], pn1 = sPn[p][1], pn2 = sPn[p][2];
    const float v0 = fmaxf(bb.x + pn0 * w0.x + pn1 * w1v.x + pn2 * w2v.x, 0.f);
    const float v1 = fmaxf(bb.y + pn0 * w0.y + pn1 * w1v.y + pn2 * w2v.y, 0.f);
    const unsigned pk = (unsigned)f2bf(v0) | ((unsigned)f2bf(v1) << 16);
    *(unsigned*)(sHraw + p * 512 + (((unsigned)(h2 * 4)) ^ ((unsigned)(p & 7) << 4))) = pk;
  }
  __syncthreads();

  // ---- phase 3: layer 2 via MFMA + bilinear + write
  const int wv = tid >> 6;
  const int lane = tid & 63;
  const int lrow = lane & 15;
  const int g = lane >> 4;

  // B fragments: wave wv owns channel groups cg = wv*2, wv*2+1 (32 channels)
  v8s fb[2][8];
#pragma unroll
  for (int ct = 0; ct < 2; ++ct) {
    const int cg = wv * 2 + ct;
#pragma unroll
    for (int ks = 0; ks < 8; ++ks)
      fb[ct][ks] = *(const v8s*)(W2bf + (size_t)(((cg * 8 + ks) * 64 + lane)) * 8);
  }

  const float* featc = featT + (size_t)bn * LL * CC;

  for (int pt = 0; pt < NP / 16; ++pt) {
    const int p0 = pt * 16;
    const int arow = p0 + lrow;
    const unsigned swz = ((unsigned)(arow & 7)) << 4;
    v8s fa[8];
#pragma unroll
    for (int ks = 0; ks < 8; ++ks) {
      const unsigned off = (unsigned)(arow * 512) + (((unsigned)(ks * 64 + g * 16)) ^ swz);
      fa[ks] = *(const v8s*)(sHraw + off);
    }
#pragma unroll
    for (int ct = 0; ct < 2; ++ct) {
      v4f acc = {0.f, 0.f, 0.f, 0.f};
#pragma unroll
      for (int ks = 0; ks < 8; ++ks)
        acc = __builtin_amdgcn_mfma_f32_16x16x32_bf16(fa[ks], fb[ct][ks], acc, 0, 0, 0);
      const int c = (wv * 2 + ct) * 16 + lrow;
      const float biasc = b2[c];
#pragma unroll
      for (int r = 0; r < 4; ++r) {
        const int lp = p0 + g * 4 + r;  // C/D layout: row=(lane>>4)*4+r, col=lane&15
        float v = acc[r] + biasc;
#pragma unroll
        for (int corner = 0; corner < 4; ++corner) {
          const float w = sW[lp][corner];
          const int off = sOff[lp][corner];
          v += w * featc[(size_t)off * CC + c];
        }
        const int ql = lp / P2;
        const int p = lp - ql * P2;
        const size_t ptg = (size_t)(blockIdx.x * NQB + ql) * P2 + p;
        out[ptg * CC + c] = v;
      }
    }
  }
}

// ---------------- fallback (round-1 kernel, direct (BN,C,H,W) gather) ----------------
__global__ __launch_bounds__(128) void gauss_fb(
    const float* __restrict__ means3D, const float* __restrict__ feat,
    const float* __restrict__ dvec, const float* __restrict__ cov3D,
    const float* __restrict__ l2i, const float* __restrict__ W1,
    const float* __restrict__ b1, const float* __restrict__ W2,
    const float* __restrict__ b2, float* __restrict__ out) {
  const int l = blockIdx.x;
  const int bn = blockIdx.y;
  const int tid = threadIdx.x;
  __shared__ float sH[P2][HID];
  __shared__ float sPn[P2][3];
  __shared__ float sW[P2][4];
  __shared__ int sOff[P2][4];
  if (tid < P2) {
    const int p = tid;
    const size_t base3 = ((size_t)bn * LL + l) * 3;
    const float m0 = means3D[base3 + 0], m1 = means3D[base3 + 1], m2 = means3D[base3 + 2];
    const float d0 = dvec[base3 + 0], d1 = dvec[base3 + 1], d2 = dvec[base3 + 2];
    const float* cv = cov3D + ((size_t)bn * LL + l) * 9;
    const float q = d0 * (cv[0] * d0 + cv[1] * d1 + cv[2] * d2) +
                    d1 * (cv[3] * d0 + cv[4] * d1 + cv[5] * d2) +
                    d2 * (cv[6] * d0 + cv[7] * d1 + cv[8] * d2);
    const float s = sqrtf(q);
    const int k = p >> 2, j = p & 3;
    const float a = (-1.5f + 0.75f * (float)k) * s;
    const float tt = -0.5f + (1.0f / 3.0f) * (float)j;
    const float px = m0 + a * d0 + tt * d1;
    const float py = m1 + a * d1 - tt * d0;
    const float pz = m2 + a * d2;
    const float* M = l2i + (size_t)bn * 16;
    const float cx = M[0] * px + M[1] * py + M[2] * pz + M[3];
    const float cy = M[4] * px + M[5] * py + M[6] * pz + M[7];
    const float cz = M[8] * px + M[9] * py + M[10] * pz + M[11];
    const float homo = fmaxf(cz, 1e-6f);
    const float u = cx / homo;
    const float v = cy / homo;
    float* camo = out + OUT_CAM_OFF + (((size_t)bn * LL + l) * P2 + p) * 2;
    camo[0] = u;
    camo[1] = v;
    float* ptso = out + OUT_PTS_OFF + (((size_t)bn * LL + l) * P2 + p) * 3;
    ptso[0] = px;
    ptso[1] = py;
    ptso[2] = pz;
    const float x = u * 0.125f - 0.5f;
    const float y = v * 0.125f - 0.5f;
    const float x0f = floorf(x), y0f = floorf(y);
    const float wx = x - x0f, wy = y - y0f;
    const bool vx0 = (x0f >= 0.f) && (x0f < (float)WG);
    const bool vx1 = (x0f + 1.f >= 0.f) && (x0f + 1.f < (float)WG);
    const bool vy0 = (y0f >= 0.f) && (y0f < (float)HG);
    const bool vy1 = (y0f + 1.f >= 0.f) && (y0f + 1.f < (float)HG);
    const int ix0 = (int)fminf(fmaxf(x0f, 0.f), (float)(WG - 1));
    const int ix1 = (int)fminf(fmaxf(x0f + 1.f, 0.f), (float)(WG - 1));
    const int iy0 = (int)fminf(fmaxf(y0f, 0.f), (float)(HG - 1));
    const int iy1 = (int)fminf(fmaxf(y0f + 1.f, 0.f), (float)(HG - 1));
    sOff[p][0] = iy0 * WG + ix0;
    sOff[p][1] = iy0 * WG + ix1;
    sOff[p][2] = iy1 * WG + ix0;
    sOff[p][3] = iy1 * WG + ix1;
    sW[p][0] = (vx0 && vy0) ? (1.f - wx) * (1.f - wy) : 0.f;
    sW[p][1] = (vx1 && vy0) ? wx * (1.f - wy) : 0.f;
    sW[p][2] = (vx0 && vy1) ? (1.f - wx) * wy : 0.f;
    sW[p][3] = (vx1 && vy1) ? wx * wy : 0.f;
    sPn[p][0] = fminf(fmaxf((px + 50.f) * 0.01f, 0.f), 1.f);
    sPn[p][1] = fminf(fmaxf((py + 50.f) * 0.01f, 0.f), 1.f);
    sPn[p][2] = fminf(fmaxf((pz + 4.f) * 0.125f, 0.f), 1.f);
  }
  __syncthreads();
  for (int u0 = tid; u0 < P2 * HID; u0 += 128) {
    const int p = u0 >> 8;
    const int h = u0 & (HID - 1);
    const float v = b1[h] + sPn[p][0] * W1[h] + sPn[p][1] * W1[HID + h] + sPn[p][2] * W1[2 * HID + h];
    sH[p][h] = fmaxf(v, 0.f);
  }
  __syncthreads();
  const int pg = tid >> 5;
  const int c0 = (tid & 31) * 4;
  const int pbase = pg * 5;
  float acc[5][4];
#pragma unroll
  for (int i = 0; i < 5; ++i)
#pragma unroll
    for (int j2 = 0; j2 < 4; ++j2) acc[i][j2] = 0.f;
  for (int h = 0; h < HID; h += 4) {
    const float4 w0 = *(const float4*)(W2 + (size_t)(h + 0) * CC + c0);
    const float4 w1 = *(const float4*)(W2 + (size_t)(h + 1) * CC + c0);
    const float4 w2 = *(const float4*)(W2 + (size_t)(h + 2) * CC + c0);
    const float4 w3 = *(const float4*)(W2 + (size_t)(h + 3) * CC + c0);
#pragma unroll
    for (int i = 0; i < 5; ++i) {
      const float4 hv = *(const float4*)(&sH[pbase + i][h]);
      acc[i][0] += hv.x * w0.x + hv.y * w1.x + hv.z * w2.x + hv.w * w3.x;
      acc[i][1] += hv.x * w0.y + hv.y * w1.y + hv.z * w2.y + hv.w * w3.y;
      acc[i][2] += hv.x * w0.z + hv.y * w1.z + hv.z * w2.z + hv.w * w3.z;
      acc[i][3] += hv.x * w0.w + hv.y * w1.w + hv.z * w2.w + hv.w * w3.w;
    }
  }
  const float4 bias = *(const float4*)(b2 + c0);
  const float* fbase = feat + (size_t)bn * CC * LL;
#pragma unroll
  for (int i = 0; i < 5; ++i) {
    const int p = pbase + i;
    float4 r;
    r.x = acc[i][0] + bias.x;
    r.y = acc[i][1] + bias.y;
    r.z = acc[i][2] + bias.z;
    r.w = acc[i][3] + bias.w;
#pragma unroll
    for (int corner = 0; corner < 4; ++corner) {
      const float w = sW[p][corner];
      const int off = sOff[p][corner];
      r.x += w * fbase[(size_t)(c0 + 0) * LL + off];
      r.y += w * fbase[(size_t)(c0 + 1) * LL + off];
      r.z += w * fbase[(size_t)(c0 + 2) * LL + off];
      r.w += w * fbase[(size_t)(c0 + 3) * LL + off];
    }
    *(float4*)(out + (((size_t)bn * LL + l) * P2 + p) * CC + c0) = r;
  }
}

extern "C" void kernel_launch(void* const* d_in, const int* in_sizes, int n_in,
                              void* d_out, int out_size, void* d_ws, size_t ws_size,
                              hipStream_t stream) {
  const float* means3D = (const float*)d_in[0];
  const float* img = (const float*)d_in[1];
  const float* dvec = (const float*)d_in[2];
  const float* cov3D = (const float*)d_in[3];
  const float* l2i = (const float*)d_in[4];
  const float* W1 = (const float*)d_in[5];
  const float* b1 = (const float*)d_in[6];
  const float* W2 = (const float*)d_in[7];
  const float* b2 = (const float*)d_in[8];
  float* out = (float*)d_out;

  const size_t w2bf_bytes = 65536;
  const size_t tbytes = (size_t)BN * LL * CC * sizeof(float);
  if (ws_size >= w2bf_bytes + tbytes) {
    unsigned short* W2bf = (unsigned short*)d_ws;
    float* featT = (float*)((char*)d_ws + w2bf_bytes);
    hipLaunchKernelGGL(pack_w2_k, dim3(16), dim3(256), 0, stream, W2, W2bf);
    hipLaunchKernelGGL(transpose_feat_k, dim3((LL + 63) / 64, CC / 64, BN), dim3(256), 0,
                       stream, img, featT);
    hipLaunchKernelGGL(gauss_mfma, dim3((BN * LL) / NQB), dim3(256), 0, stream, means3D, featT,
                       dvec, cov3D, l2i, W1, b1, W2bf, b2, out);
  } else {
    hipLaunchKernelGGL(gauss_fb, dim3(LL, BN), dim3(128), 0, stream, means3D, img, dvec, cov3D,
                       l2i, W1, b1, W2, b2, out);
  }
}

// Round 3
// 97.646 us; speedup vs baseline: 4.7658x; 1.4984x over previous
//
#include <hip/hip_runtime.h>
#include <math.h>

#define BN 12
#define HG 28
#define WG 60
#define LL 1680      // HG*WG
#define CC 128
#define P2 20
#define HID 256
#define NPTS (BN * LL * P2)  // 403200
#define NPB 64               // points per block in gemm kernel
#define NQB 4                // queries per block (mid fallback)
#define NP (NQB * P2)

static constexpr size_t OUT_CAM_OFF = (size_t)BN * LL * P2 * CC;              // 51609600
static constexpr size_t OUT_PTS_OFF = OUT_CAM_OFF + (size_t)BN * LL * P2 * 2; // 52416000

typedef short v8s __attribute__((ext_vector_type(8)));
typedef float v4f __attribute__((ext_vector_type(4)));
typedef unsigned long long u64;

__device__ __forceinline__ unsigned short f2bf(float f) {
  unsigned x = __float_as_uint(f);
  unsigned r = (x + 0x7FFFu + ((x >> 16) & 1u)) >> 16;
  return (unsigned short)r;
}

// ---------------- transpose img_features (BN,C,L) -> (BN,L,C) ----------------
__global__ __launch_bounds__(256) void transpose_feat_k(const float* __restrict__ in,
                                                        float* __restrict__ out) {
  __shared__ float tile[64][65];
  const int bn = blockIdx.z;
  const int c0 = blockIdx.y * 64;
  const int l0 = blockIdx.x * 64;
  const int t = threadIdx.x;
  {
    const int lx = t & 63;
    const int cy = t >> 6;
#pragma unroll
    for (int i = 0; i < 64; i += 4) {
      const int c = c0 + cy + i;
      const int l = l0 + lx;
      float v = 0.f;
      if (l < LL) v = in[((size_t)bn * CC + c) * LL + l];
      tile[cy + i][lx] = v;
    }
  }
  __syncthreads();
  {
    const int cx = t & 63;
    const int ly = t >> 6;
#pragma unroll
    for (int i = 0; i < 64; i += 4) {
      const int l = l0 + ly + i;
      const int c = c0 + cx;
      if (l < LL) out[((size_t)bn * LL + l) * CC + c] = tile[cx][ly + i];
    }
  }
}

// ---------------- pack W2 (256x128 f32) into bf16 B-fragment order ----------------
__global__ __launch_bounds__(256) void pack_w2_k(const float* __restrict__ W2,
                                                 unsigned short* __restrict__ W2bf) {
  const int t = blockIdx.x * 256 + threadIdx.x;
  if (t >= 4096) return;
  const int lane = t & 63;
  const int ks = (t >> 6) & 7;
  const int cg = t >> 9;
  const int col = cg * 16 + (lane & 15);
  const int kb = ks * 32 + (lane >> 4) * 8;
  v8s r;
#pragma unroll
  for (int e = 0; e < 8; ++e) r[e] = (short)f2bf(W2[(size_t)(kb + e) * CC + col]);
  *(v8s*)(W2bf + (size_t)t * 8) = r;
}

// ---------------- kernel A: geometry, cam/pts outputs, per-point records ----------------
__global__ __launch_bounds__(256) void geom_k(const float* __restrict__ means3D,
                                              const float* __restrict__ dvec,
                                              const float* __restrict__ cov3D,
                                              const float* __restrict__ l2i,
                                              float* __restrict__ out,
                                              u64* __restrict__ off8,
                                              float4* __restrict__ w4,
                                              float4* __restrict__ pn4) {
  const int pid = blockIdx.x * 256 + threadIdx.x;
  if (pid >= NPTS) return;
  const unsigned qg = (unsigned)pid / P2;
  const int p = pid - (int)qg * P2;
  const unsigned bn = qg / LL;

  const size_t base3 = (size_t)qg * 3;
  const float m0 = means3D[base3 + 0], m1 = means3D[base3 + 1], m2 = means3D[base3 + 2];
  const float d0 = dvec[base3 + 0], d1 = dvec[base3 + 1], d2 = dvec[base3 + 2];
  const float* cv = cov3D + (size_t)qg * 9;
  const float q = d0 * (cv[0] * d0 + cv[1] * d1 + cv[2] * d2) +
                  d1 * (cv[3] * d0 + cv[4] * d1 + cv[5] * d2) +
                  d2 * (cv[6] * d0 + cv[7] * d1 + cv[8] * d2);
  const float s = sqrtf(q);
  const int k = p >> 2, j = p & 3;
  const float a = (-1.5f + 0.75f * (float)k) * s;     // lin5[k]*sqrt(q)
  const float tt = -0.5f + (1.0f / 3.0f) * (float)j;  // linP[j]
  const float px = m0 + a * d0 + tt * d1;
  const float py = m1 + a * d1 - tt * d0;
  const float pz = m2 + a * d2;
  const float* M = l2i + (size_t)bn * 16;
  const float cx = M[0] * px + M[1] * py + M[2] * pz + M[3];
  const float cy = M[4] * px + M[5] * py + M[6] * pz + M[7];
  const float cz = M[8] * px + M[9] * py + M[10] * pz + M[11];
  const float homo = fmaxf(cz, 1e-6f);
  const float u = cx / homo;
  const float v = cy / homo;

  *(float2*)(out + OUT_CAM_OFF + (size_t)pid * 2) = make_float2(u, v);
  float* ptso = out + OUT_PTS_OFF + (size_t)pid * 3;
  ptso[0] = px;
  ptso[1] = py;
  ptso[2] = pz;

  const float x = u * 0.125f - 0.5f;
  const float y = v * 0.125f - 0.5f;
  const float x0f = floorf(x), y0f = floorf(y);
  const float wx = x - x0f, wy = y - y0f;
  const bool vx0 = (x0f >= 0.f) && (x0f < (float)WG);
  const bool vx1 = (x0f + 1.f >= 0.f) && (x0f + 1.f < (float)WG);
  const bool vy0 = (y0f >= 0.f) && (y0f < (float)HG);
  const bool vy1 = (y0f + 1.f >= 0.f) && (y0f + 1.f < (float)HG);
  const unsigned ix0 = (unsigned)(int)fminf(fmaxf(x0f, 0.f), (float)(WG - 1));
  const unsigned ix1 = (unsigned)(int)fminf(fmaxf(x0f + 1.f, 0.f), (float)(WG - 1));
  const unsigned iy0 = (unsigned)(int)fminf(fmaxf(y0f, 0.f), (float)(HG - 1));
  const unsigned iy1 = (unsigned)(int)fminf(fmaxf(y0f + 1.f, 0.f), (float)(HG - 1));
  const u64 o0 = (u64)(iy0 * WG + ix0);
  const u64 o1 = (u64)(iy0 * WG + ix1);
  const u64 o2 = (u64)(iy1 * WG + ix0);
  const u64 o3 = (u64)(iy1 * WG + ix1);
  off8[pid] = o0 | (o1 << 16) | (o2 << 32) | (o3 << 48);
  w4[pid] = make_float4((vx0 && vy0) ? (1.f - wx) * (1.f - wy) : 0.f,
                        (vx1 && vy0) ? wx * (1.f - wy) : 0.f,
                        (vx0 && vy1) ? (1.f - wx) * wy : 0.f,
                        (vx1 && vy1) ? wx * wy : 0.f);
  pn4[pid] = make_float4(fminf(fmaxf((px + 50.f) * 0.01f, 0.f), 1.f),
                         fminf(fmaxf((py + 50.f) * 0.01f, 0.f), 1.f),
                         fminf(fmaxf((pz + 4.f) * 0.125f, 0.f), 1.f), 0.f);
}

// ---------------- kernel B: MLP via MFMA + bilinear gather + coalesced write ----------------
// 64 points/block, 256 threads (4 waves). LDS region sH is used 3 ways under one
// XOR swizzle (byte ^= (row&7)<<4): bf16 H rows (write b64 / read b128 A-frags),
// then f32 transposed output rows (write b32 / read b128). In-place tile overwrite
// guarded by 2 barriers per 16-point tile.
__global__ __launch_bounds__(256, 4) void gemm_k(
    const float* __restrict__ featT,  // (BN,L,C)
    const float* __restrict__ W1,
    const float* __restrict__ b1,
    const unsigned short* __restrict__ W2bf,
    const float* __restrict__ b2,
    const u64* __restrict__ off8,
    const float4* __restrict__ w4,
    const float4* __restrict__ pn4,
    float* __restrict__ out) {
  const int tid = threadIdx.x;
  const int gp0 = blockIdx.x * NPB;
  const int bn = blockIdx.x / 525;  // 33600 points per bn / 64 = 525; blocks never span bn

  __shared__ __align__(16) char sH[NPB * 512];
  __shared__ u64 sOff8[NPB];
  __shared__ float4 sWl[NPB];
  __shared__ float4 sPnl[NPB];

  // stage per-point records (coalesced)
  if (tid < NPB) {
    sOff8[tid] = off8[gp0 + tid];
    sWl[tid] = w4[gp0 + tid];
    sPnl[tid] = pn4[gp0 + tid];
  }

  const int wv = tid >> 6;
  const int lane = tid & 63;
  const int lrow = lane & 15;
  const int g = lane >> 4;

  // B-fragments for this wave's 32 channels (issued early; latency hides under phase A)
  v8s fb0[8], fb1[8];
#pragma unroll
  for (int ks = 0; ks < 8; ++ks) {
    fb0[ks] = *(const v8s*)(W2bf + (size_t)(((wv * 2 + 0) * 8 + ks) * 64 + lane) * 8);
    fb1[ks] = *(const v8s*)(W2bf + (size_t)(((wv * 2 + 1) * 8 + ks) * 64 + lane) * 8);
  }

  // W1/b1 slice: loaded ONCE (h4 is loop-invariant per thread)
  const int h4 = (tid & 63) * 4;
  const int pw = tid >> 6;
  const float4 a0 = *(const float4*)(W1 + h4);
  const float4 a1 = *(const float4*)(W1 + HID + h4);
  const float4 a2 = *(const float4*)(W1 + 2 * HID + h4);
  const float4 bb = *(const float4*)(b1 + h4);

  __syncthreads();

  // phase A: H[64][256] = relu(pn @ W1 + b1) -> bf16 LDS (swizzled), b64 writes
#pragma unroll
  for (int it = 0; it < NPB / 4; ++it) {
    const int p = it * 4 + pw;
    const float4 pn = sPnl[p];
    const float v0 = fmaxf(bb.x + pn.x * a0.x + pn.y * a1.x + pn.z * a2.x, 0.f);
    const float v1 = fmaxf(bb.y + pn.x * a0.y + pn.y * a1.y + pn.z * a2.y, 0.f);
    const float v2 = fmaxf(bb.z + pn.x * a0.z + pn.y * a1.z + pn.z * a2.z, 0.f);
    const float v3 = fmaxf(bb.w + pn.x * a0.w + pn.y * a1.w + pn.z * a2.w, 0.f);
    const u64 pk = (u64)f2bf(v0) | ((u64)f2bf(v1) << 16) | ((u64)f2bf(v2) << 32) |
                   ((u64)f2bf(v3) << 48);
    *(u64*)(sH + p * 512 + (((unsigned)(h4 * 2)) ^ (((unsigned)(p & 7)) << 4))) = pk;
  }
  __syncthreads();

  // phase B: per 16-point tile: MFMA then in-place transpose into the same rows
  for (int pt = 0; pt < 4; ++pt) {
    const int arow = pt * 16 + lrow;
    const unsigned swz = ((unsigned)(arow & 7)) << 4;
    v8s fa[8];
#pragma unroll
    for (int ks = 0; ks < 8; ++ks)
      fa[ks] = *(const v8s*)(sH + arow * 512 + (((unsigned)(ks * 64 + g * 16)) ^ swz));
    v4f acc0 = {0.f, 0.f, 0.f, 0.f};
    v4f acc1 = {0.f, 0.f, 0.f, 0.f};
#pragma unroll
    for (int ks = 0; ks < 8; ++ks)
      acc0 = __builtin_amdgcn_mfma_f32_16x16x32_bf16(fa[ks], fb0[ks], acc0, 0, 0, 0);
#pragma unroll
    for (int ks = 0; ks < 8; ++ks)
      acc1 = __builtin_amdgcn_mfma_f32_16x16x32_bf16(fa[ks], fb1[ks], acc1, 0, 0, 0);
    __syncthreads();  // all waves done reading H rows of this tile
#pragma unroll
    for (int r = 0; r < 4; ++r) {
      const int lp = pt * 16 + g * 4 + r;  // C/D: row=(lane>>4)*4+r, col=lane&15
      const unsigned s2 = ((unsigned)(lp & 7)) << 4;
      const int c0 = wv * 32 + lrow;
      *(float*)(sH + lp * 512 + (((unsigned)(c0 * 4)) ^ s2)) = acc0[r];
      *(float*)(sH + lp * 512 + (((unsigned)((c0 + 16) * 4)) ^ s2)) = acc1[r];
    }
    __syncthreads();  // writes visible before next tile / epilogue
  }

  // epilogue: bias + bilinear gather + fully-coalesced float4 stores
  const float* featc = featT + (size_t)bn * (LL * CC);
#pragma unroll
  for (int it = 0; it < 8; ++it) {
    const int p = it * 8 + (tid >> 5);
    const int c4g = tid & 31;
    const unsigned boff =
        (unsigned)(p * 512) + (((unsigned)(c4g * 16)) ^ (((unsigned)(p & 7)) << 4));
    const v4f t = *(const v4f*)(sH + boff);
    const u64 o8 = sOff8[p];
    const float4 w = sWl[p];
    const float4 bias = *(const float4*)(b2 + c4g * 4);
    float rx = t[0] + bias.x, ry = t[1] + bias.y, rz = t[2] + bias.z, rw = t[3] + bias.w;
    {
      const float4 f = *(const float4*)(featc + (size_t)(unsigned)(o8 & 0xFFFFu) * CC + c4g * 4);
      rx += w.x * f.x; ry += w.x * f.y; rz += w.x * f.z; rw += w.x * f.w;
    }
    {
      const float4 f =
          *(const float4*)(featc + (size_t)(unsigned)((o8 >> 16) & 0xFFFFu) * CC + c4g * 4);
      rx += w.y * f.x; ry += w.y * f.y; rz += w.y * f.z; rw += w.y * f.w;
    }
    {
      const float4 f =
          *(const float4*)(featc + (size_t)(unsigned)((o8 >> 32) & 0xFFFFu) * CC + c4g * 4);
      rx += w.z * f.x; ry += w.z * f.y; rz += w.z * f.z; rw += w.z * f.w;
    }
    {
      const float4 f =
          *(const float4*)(featc + (size_t)(unsigned)((o8 >> 48) & 0xFFFFu) * CC + c4g * 4);
      rx += w.w * f.x; ry += w.w * f.y; rz += w.w * f.z; rw += w.w * f.w;
    }
    *(float4*)(out + (size_t)(gp0 + p) * CC + c4g * 4) = make_float4(rx, ry, rz, rw);
  }
}

// ---------------- mid fallback: R2 fused kernel (4 queries/block) ----------------
__global__ __launch_bounds__(256, 3) void gauss_mfma(
    const float* __restrict__ means3D, const float* __restrict__ featT,
    const float* __restrict__ dvec, const float* __restrict__ cov3D,
    const float* __restrict__ l2i, const float* __restrict__ W1,
    const float* __restrict__ b1, const unsigned short* __restrict__ W2bf,
    const float* __restrict__ b2, float* __restrict__ out) {
  const int tid = threadIdx.x;
  const int bn = blockIdx.x / (LL / NQB);
  __shared__ __align__(16) char sHraw[NP * 512];
  __shared__ float sW[NP][4];
  __shared__ int sOff[NP][4];
  __shared__ float sPn[NP][3];
  if (tid < NP) {
    const int lp = tid;
    const int ql = lp / P2;
    const int p = lp - ql * P2;
    const int qg = blockIdx.x * NQB + ql;
    const size_t base3 = (size_t)qg * 3;
    const float m0 = means3D[base3 + 0], m1 = means3D[base3 + 1], m2 = means3D[base3 + 2];
    const float d0 = dvec[base3 + 0], d1 = dvec[base3 + 1], d2 = dvec[base3 + 2];
    const float* cv = cov3D + (size_t)qg * 9;
    const float q = d0 * (cv[0] * d0 + cv[1] * d1 + cv[2] * d2) +
                    d1 * (cv[3] * d0 + cv[4] * d1 + cv[5] * d2) +
                    d2 * (cv[6] * d0 + cv[7] * d1 + cv[8] * d2);
    const float s = sqrtf(q);
    const int k = p >> 2, j = p & 3;
    const float a = (-1.5f + 0.75f * (float)k) * s;
    const float tt = -0.5f + (1.0f / 3.0f) * (float)j;
    const float px = m0 + a * d0 + tt * d1;
    const float py = m1 + a * d1 - tt * d0;
    const float pz = m2 + a * d2;
    const float* M = l2i + (size_t)bn * 16;
    const float cx = M[0] * px + M[1] * py + M[2] * pz + M[3];
    const float cy = M[4] * px + M[5] * py + M[6] * pz + M[7];
    const float cz = M[8] * px + M[9] * py + M[10] * pz + M[11];
    const float homo = fmaxf(cz, 1e-6f);
    const float u = cx / homo;
    const float v = cy / homo;
    const size_t ptg = (size_t)qg * P2 + p;
    float* camo = out + OUT_CAM_OFF + ptg * 2;
    camo[0] = u;
    camo[1] = v;
    float* ptso = out + OUT_PTS_OFF + ptg * 3;
    ptso[0] = px;
    ptso[1] = py;
    ptso[2] = pz;
    const float x = u * 0.125f - 0.5f;
    const float y = v * 0.125f - 0.5f;
    const float x0f = floorf(x), y0f = floorf(y);
    const float wx = x - x0f, wy = y - y0f;
    const bool vx0 = (x0f >= 0.f) && (x0f < (float)WG);
    const bool vx1 = (x0f + 1.f >= 0.f) && (x0f + 1.f < (float)WG);
    const bool vy0 = (y0f >= 0.f) && (y0f < (float)HG);
    const bool vy1 = (y0f + 1.f >= 0.f) && (y0f + 1.f < (float)HG);
    const int ix0 = (int)fminf(fmaxf(x0f, 0.f), (float)(WG - 1));
    const int ix1 = (int)fminf(fmaxf(x0f + 1.f, 0.f), (float)(WG - 1));
    const int iy0 = (int)fminf(fmaxf(y0f, 0.f), (float)(HG - 1));
    const int iy1 = (int)fminf(fmaxf(y0f + 1.f, 0.f), (float)(HG - 1));
    sOff[lp][0] = iy0 * WG + ix0;
    sOff[lp][1] = iy0 * WG + ix1;
    sOff[lp][2] = iy1 * WG + ix0;
    sOff[lp][3] = iy1 * WG + ix1;
    sW[lp][0] = (vx0 && vy0) ? (1.f - wx) * (1.f - wy) : 0.f;
    sW[lp][1] = (vx1 && vy0) ? wx * (1.f - wy) : 0.f;
    sW[lp][2] = (vx0 && vy1) ? (1.f - wx) * wy : 0.f;
    sW[lp][3] = (vx1 && vy1) ? wx * wy : 0.f;
    sPn[lp][0] = fminf(fmaxf((px + 50.f) * 0.01f, 0.f), 1.f);
    sPn[lp][1] = fminf(fmaxf((py + 50.f) * 0.01f, 0.f), 1.f);
    sPn[lp][2] = fminf(fmaxf((pz + 4.f) * 0.125f, 0.f), 1.f);
  }
  __syncthreads();
#pragma unroll
  for (int it = 0; it < (NP * 128) / 256; ++it) {
    const int u0 = it * 256 + tid;
    const int h2 = u0 & 127;
    const int p = u0 >> 7;
    const float2 bbv = *(const float2*)(b1 + 2 * h2);
    const float2 w0 = *(const float2*)(W1 + 2 * h2);
    const float2 w1v = *(const float2*)(W1 + HID + 2 * h2);
    const float2 w2v = *(const float2*)(W1 + 2 * HID + 2 * h2);
    const float pn0 = sPn[p][0], pn1 = sPn[p][1], pn2 = sPn[p][2];
    const float v0 = fmaxf(bbv.x + pn0 * w0.x + pn1 * w1v.x + pn2 * w2v.x, 0.f);
    const float v1 = fmaxf(bbv.y + pn0 * w0.y + pn1 * w1v.y + pn2 * w2v.y, 0.f);
    const unsigned pk = (unsigned)f2bf(v0) | ((unsigned)f2bf(v1) << 16);
    *(unsigned*)(sHraw + p * 512 + (((unsigned)(h2 * 4)) ^ ((unsigned)(p & 7) << 4))) = pk;
  }
  __syncthreads();
  const int wv = tid >> 6;
  const int lane = tid & 63;
  const int lrow = lane & 15;
  const int g = lane >> 4;
  v8s fb[2][8];
#pragma unroll
  for (int ct = 0; ct < 2; ++ct) {
    const int cg = wv * 2 + ct;
#pragma unroll
    for (int ks = 0; ks < 8; ++ks)
      fb[ct][ks] = *(const v8s*)(W2bf + (size_t)(((cg * 8 + ks) * 64 + lane)) * 8);
  }
  const float* featc = featT + (size_t)bn * LL * CC;
  for (int pt = 0; pt < NP / 16; ++pt) {
    const int p0 = pt * 16;
    const int arow = p0 + lrow;
    const unsigned swz = ((unsigned)(arow & 7)) << 4;
    v8s fa[8];
#pragma unroll
    for (int ks = 0; ks < 8; ++ks) {
      const unsigned off = (unsigned)(arow * 512) + (((unsigned)(ks * 64 + g * 16)) ^ swz);
      fa[ks] = *(const v8s*)(sHraw + off);
    }
#pragma unroll
    for (int ct = 0; ct < 2; ++ct) {
      v4f acc = {0.f, 0.f, 0.f, 0.f};
#pragma unroll
      for (int ks = 0; ks < 8; ++ks)
        acc = __builtin_amdgcn_mfma_f32_16x16x32_bf16(fa[ks], fb[ct][ks], acc, 0, 0, 0);
      const int c = (wv * 2 + ct) * 16 + lrow;
      const float biasc = b2[c];
#pragma unroll
      for (int r = 0; r < 4; ++r) {
        const int lp = p0 + g * 4 + r;
        float v = acc[r] + biasc;
#pragma unroll
        for (int corner = 0; corner < 4; ++corner) {
          v += sW[lp][corner] * featc[(size_t)sOff[lp][corner] * CC + c];
        }
        const int ql = lp / P2;
        const int p = lp - ql * P2;
        const size_t ptg = (size_t)(blockIdx.x * NQB + ql) * P2 + p;
        out[ptg * CC + c] = v;
      }
    }
  }
}

// ---------------- last-resort fallback (no ws): R1 fused fp32 kernel ----------------
__global__ __launch_bounds__(128) void gauss_fb(
    const float* __restrict__ means3D, const float* __restrict__ feat,
    const float* __restrict__ dvec, const float* __restrict__ cov3D,
    const float* __restrict__ l2i, const float* __restrict__ W1,
    const float* __restrict__ b1, const float* __restrict__ W2,
    const float* __restrict__ b2, float* __restrict__ out) {
  const int l = blockIdx.x;
  const int bn = blockIdx.y;
  const int tid = threadIdx.x;
  __shared__ float sH[P2][HID];
  __shared__ float sPn[P2][3];
  __shared__ float sW[P2][4];
  __shared__ int sOff[P2][4];
  if (tid < P2) {
    const int p = tid;
    const size_t base3 = ((size_t)bn * LL + l) * 3;
    const float m0 = means3D[base3 + 0], m1 = means3D[base3 + 1], m2 = means3D[base3 + 2];
    const float d0 = dvec[base3 + 0], d1 = dvec[base3 + 1], d2 = dvec[base3 + 2];
    const float* cv = cov3D + ((size_t)bn * LL + l) * 9;
    const float q = d0 * (cv[0] * d0 + cv[1] * d1 + cv[2] * d2) +
                    d1 * (cv[3] * d0 + cv[4] * d1 + cv[5] * d2) +
                    d2 * (cv[6] * d0 + cv[7] * d1 + cv[8] * d2);
    const float s = sqrtf(q);
    const int k = p >> 2, j = p & 3;
    const float a = (-1.5f + 0.75f * (float)k) * s;
    const float tt = -0.5f + (1.0f / 3.0f) * (float)j;
    const float px = m0 + a * d0 + tt * d1;
    const float py = m1 + a * d1 - tt * d0;
    const float pz = m2 + a * d2;
    const float* M = l2i + (size_t)bn * 16;
    const float cx = M[0] * px + M[1] * py + M[2] * pz + M[3];
    const float cy = M[4] * px + M[5] * py + M[6] * pz + M[7];
    const float cz = M[8] * px + M[9] * py + M[10] * pz + M[11];
    const float homo = fmaxf(cz, 1e-6f);
    const float u = cx / homo;
    const float v = cy / homo;
    float* camo = out + OUT_CAM_OFF + (((size_t)bn * LL + l) * P2 + p) * 2;
    camo[0] = u;
    camo[1] = v;
    float* ptso = out + OUT_PTS_OFF + (((size_t)bn * LL + l) * P2 + p) * 3;
    ptso[0] = px;
    ptso[1] = py;
    ptso[2] = pz;
    const float x = u * 0.125f - 0.5f;
    const float y = v * 0.125f - 0.5f;
    const float x0f = floorf(x), y0f = floorf(y);
    const float wx = x - x0f, wy = y - y0f;
    const bool vx0 = (x0f >= 0.f) && (x0f < (float)WG);
    const bool vx1 = (x0f + 1.f >= 0.f) && (x0f + 1.f < (float)WG);
    const bool vy0 = (y0f >= 0.f) && (y0f < (float)HG);
    const bool vy1 = (y0f + 1.f >= 0.f) && (y0f + 1.f < (float)HG);
    const int ix0 = (int)fminf(fmaxf(x0f, 0.f), (float)(WG - 1));
    const int ix1 = (int)fminf(fmaxf(x0f + 1.f, 0.f), (float)(WG - 1));
    const int iy0 = (int)fminf(fmaxf(y0f, 0.f), (float)(HG - 1));
    const int iy1 = (int)fminf(fmaxf(y0f + 1.f, 0.f), (float)(HG - 1));
    sOff[p][0] = iy0 * WG + ix0;
    sOff[p][1] = iy0 * WG + ix1;
    sOff[p][2] = iy1 * WG + ix0;
    sOff[p][3] = iy1 * WG + ix1;
    sW[p][0] = (vx0 && vy0) ? (1.f - wx) * (1.f - wy) : 0.f;
    sW[p][1] = (vx1 && vy0) ? wx * (1.f - wy) : 0.f;
    sW[p][2] = (vx0 && vy1) ? (1.f - wx) * wy : 0.f;
    sW[p][3] = (vx1 && vy1) ? wx * wy : 0.f;
    sPn[p][0] = fminf(fmaxf((px + 50.f) * 0.01f, 0.f), 1.f);
    sPn[p][1] = fminf(fmaxf((py + 50.f) * 0.01f, 0.f), 1.f);
    sPn[p][2] = fminf(fmaxf((pz + 4.f) * 0.125f, 0.f), 1.f);
  }
  __syncthreads();
  for (int u0 = tid; u0 < P2 * HID; u0 += 128) {
    const int p = u0 >> 8;
    const int h = u0 & (HID - 1);
    const float v = b1[h] + sPn[p][0] * W1[h] + sPn[p][1] * W1[HID + h] + sPn[p][2] * W1[2 * HID + h];
    sH[p][h] = fmaxf(v, 0.f);
  }
  __syncthreads();
  const int pg = tid >> 5;
  const int c0 = (tid & 31) * 4;
  const int pbase = pg * 5;
  float acc[5][4];
#pragma unroll
  for (int i = 0; i < 5; ++i)
#pragma unroll
    for (int j2 = 0; j2 < 4; ++j2) acc[i][j2] = 0.f;
  for (int h = 0; h < HID; h += 4) {
    const float4 w0 = *(const float4*)(W2 + (size_t)(h + 0) * CC + c0);
    const float4 w1 = *(const float4*)(W2 + (size_t)(h + 1) * CC + c0);
    const float4 w2 = *(const float4*)(W2 + (size_t)(h + 2) * CC + c0);
    const float4 w3 = *(const float4*)(W2 + (size_t)(h + 3) * CC + c0);
#pragma unroll
    for (int i = 0; i < 5; ++i) {
      const float4 hv = *(const float4*)(&sH[pbase + i][h]);
      acc[i][0] += hv.x * w0.x + hv.y * w1.x + hv.z * w2.x + hv.w * w3.x;
      acc[i][1] += hv.x * w0.y + hv.y * w1.y + hv.z * w2.y + hv.w * w3.y;
      acc[i][2] += hv.x * w0.z + hv.y * w1.z + hv.z * w2.z + hv.w * w3.z;
      acc[i][3] += hv.x * w0.w + hv.y * w1.w + hv.z * w2.w + hv.w * w3.w;
    }
  }
  const float4 bias = *(const float4*)(b2 + c0);
  const float* fbase = feat + (size_t)bn * CC * LL;
#pragma unroll
  for (int i = 0; i < 5; ++i) {
    const int p = pbase + i;
    float4 r;
    r.x = acc[i][0] + bias.x;
    r.y = acc[i][1] + bias.y;
    r.z = acc[i][2] + bias.z;
    r.w = acc[i][3] + bias.w;
#pragma unroll
    for (int corner = 0; corner < 4; ++corner) {
      const float w = sW[p][corner];
      const int off = sOff[p][corner];
      r.x += w * fbase[(size_t)(c0 + 0) * LL + off];
      r.y += w * fbase[(size_t)(c0 + 1) * LL + off];
      r.z += w * fbase[(size_t)(c0 + 2) * LL + off];
      r.w += w * fbase[(size_t)(c0 + 3) * LL + off];
    }
    *(float4*)(out + (((size_t)bn * LL + l) * P2 + p) * CC + c0) = r;
  }
}

extern "C" void kernel_launch(void* const* d_in, const int* in_sizes, int n_in,
                              void* d_out, int out_size, void* d_ws, size_t ws_size,
                              hipStream_t stream) {
  const float* means3D = (const float*)d_in[0];
  const float* img = (const float*)d_in[1];
  const float* dvec = (const float*)d_in[2];
  const float* cov3D = (const float*)d_in[3];
  const float* l2i = (const float*)d_in[4];
  const float* W1 = (const float*)d_in[5];
  const float* b1 = (const float*)d_in[6];
  const float* W2 = (const float*)d_in[7];
  const float* b2 = (const float*)d_in[8];
  float* out = (float*)d_out;

  const size_t w2bf_bytes = 65536;
  const size_t tbytes = (size_t)BN * LL * CC * sizeof(float);  // 10321920
  const size_t off8_bytes = (size_t)NPTS * 8;                  // 3225600
  const size_t w4_bytes = (size_t)NPTS * 16;                   // 6451200
  const size_t need_full = w2bf_bytes + tbytes + off8_bytes + 2 * w4_bytes;  // 26515456

  if (ws_size >= need_full) {
    unsigned short* W2bf = (unsigned short*)d_ws;
    float* featT = (float*)((char*)d_ws + w2bf_bytes);
    u64* off8 = (u64*)((char*)d_ws + w2bf_bytes + tbytes);
    float4* w4 = (float4*)((char*)d_ws + w2bf_bytes + tbytes + off8_bytes);
    float4* pn4 = (float4*)((char*)d_ws + w2bf_bytes + tbytes + off8_bytes + w4_bytes);
    hipLaunchKernelGGL(pack_w2_k, dim3(16), dim3(256), 0, stream, W2, W2bf);
    hipLaunchKernelGGL(transpose_feat_k, dim3((LL + 63) / 64, CC / 64, BN), dim3(256), 0,
                       stream, img, featT);
    hipLaunchKernelGGL(geom_k, dim3(NPTS / 256), dim3(256), 0, stream, means3D, dvec, cov3D,
                       l2i, out, off8, w4, pn4);
    hipLaunchKernelGGL(gemm_k, dim3(NPTS / NPB), dim3(256), 0, stream, featT, W1, b1, W2bf, b2,
                       off8, w4, pn4, out);
  } else if (ws_size >= w2bf_bytes + tbytes) {
    unsigned short* W2bf = (unsigned short*)d_ws;
    float* featT = (float*)((char*)d_ws + w2bf_bytes);
    hipLaunchKernelGGL(pack_w2_k, dim3(16), dim3(256), 0, stream, W2, W2bf);
    hipLaunchKernelGGL(transpose_feat_k, dim3((LL + 63) / 64, CC / 64, BN), dim3(256), 0,
                       stream, img, featT);
    hipLaunchKernelGGL(gauss_mfma, dim3((BN * LL) / NQB), dim3(256), 0, stream, means3D, featT,
                       dvec, cov3D, l2i, W1, b1, W2bf, b2, out);
  } else {
    hipLaunchKernelGGL(gauss_fb, dim3(LL, BN), dim3(128), 0, stream, means3D, img, dvec, cov3D,
                       l2i, W1, b1, W2, b2, out);
  }
}